// Round 17
// baseline (113.689 us; speedup 1.0000x reference)
//
#include <hip/hip_runtime.h>
#include <stdint.h>

using u16 = unsigned short;
typedef __attribute__((ext_vector_type(8))) short bf16x8;
typedef __attribute__((ext_vector_type(4))) float f32x4;

#define DEVI static __device__ __forceinline__

constexpr int BATCH  = 2;
constexpr int NPTS   = 50000;
constexpr int TOTPTS = BATCH * NPTS;      // 100000
constexpr int CIMG   = 256;
constexpr int MIDC   = 128;
constexpr int OUTC   = 128;
constexpr int PTSC   = 64;
constexpr int KIMG   = 384;               // 3 * 128
constexpr int KTOT   = 448;
constexpr float WPADf = 1280.f, HPADf = 384.f;
constexpr float BNEPS = 1e-3f;

DEVI u16 f2bf(float f) {                  // RNE float -> bf16 bits (prep paths)
  unsigned x = __float_as_uint(f);
  return (u16)((x + 0x7fffu + ((x >> 16) & 1u)) >> 16);
}
DEVI unsigned cvt_pk_bf16(float lo, float hi) {  // HW packed f32->2xbf16
  unsigned r;
  asm("v_cvt_pk_bf16_f32 %0, %1, %2" : "=v"(r) : "v"(lo), "v"(hi));
  return r;
}
DEVI float blo(unsigned u) { return __uint_as_float(u << 16); }
DEVI float bhi(unsigned u) { return __uint_as_float(u & 0xffff0000u); }

DEVI void gload_lds16(const void* g, void* l) {   // 16B DMA global->LDS
  __builtin_amdgcn_global_load_lds(
      (const __attribute__((address_space(1))) void*)g,
      (__attribute__((address_space(3))) void*)l, 16, 0, 0);
}

// Counted-vmcnt barrier (T4): never drain to 0 in the loop.
#define CBAR(N)                                             \
  do {                                                      \
    asm volatile("s_waitcnt vmcnt(" #N ")" ::: "memory");   \
    __builtin_amdgcn_s_barrier();                           \
    __builtin_amdgcn_sched_barrier(0);                      \
  } while (0)

// ============================ zero padded bufs =============================
__global__ __launch_bounds__(256) void zero_kernel(uint4* __restrict__ p, int n16) {
  int i = blockIdx.x * 256 + threadIdx.x;
  int stride = gridDim.x * 256;
  for (; i < n16; i += stride) p[i] = uint4{0u, 0u, 0u, 0u};
}

// ================= NCHW fp32 -> padded NHWC bf16 (per level) ===============
__global__ __launch_bounds__(256) void nchw2nhwc_kernel(
    const float* __restrict__ in, u16* __restrict__ outp, int H, int W) {
  __shared__ float s[64][33];
  const int t  = threadIdx.x;
  const int x0 = blockIdx.x * 32;
  const int y  = blockIdx.y;
  const int b  = blockIdx.z >> 2;
  const int c0 = (blockIdx.z & 3) * 64;
  #pragma unroll
  for (int i = 0; i < 8; ++i) {
    int e = t + i * 256, ci = e >> 5, xi = e & 31;
    float v = 0.f;
    if (x0 + xi < W) v = in[((size_t)(b * CIMG + c0 + ci) * H + y) * W + x0 + xi];
    s[ci][xi] = v;
  }
  __syncthreads();
  const int Wp = W + 2;
  #pragma unroll
  for (int i = 0; i < 8; ++i) {
    int e = t + i * 256, xi = e >> 6, ci = e & 63;
    if (x0 + xi < W)
      outp[((size_t)(b * (H + 2) + y + 1) * Wp + x0 + xi + 1) * CIMG + c0 + ci] =
          f2bf(s[ci][xi]);
  }
}

// ====== prep: BN-fold + bf16 frag-pack of GEMM & conv weights + bias =======
// BOTH packs use layout [ks][s(4)][col(128)][j(8)]  (k = ks*32 + s*8 + j)
__global__ __launch_bounds__(256) void prep_kernel(
    const float* __restrict__ img_w, const float* __restrict__ img_b,
    const float* __restrict__ pts_w, const float* __restrict__ pts_b,
    const float* __restrict__ ibg, const float* __restrict__ ibb,
    const float* __restrict__ ibm, const float* __restrict__ ibv,
    const float* __restrict__ pbg, const float* __restrict__ pbb,
    const float* __restrict__ pbm, const float* __restrict__ pbv,
    const float* __restrict__ lat_w,
    u16* __restrict__ wg, u16* __restrict__ wc, float* __restrict__ bias)
{
  int e = blockIdx.x * 256 + threadIdx.x;
  if (e < 57344) {                                   // GEMM pack 14*4*128*8
    int j = e & 7, c = (e >> 3) & 127, s = (e >> 10) & 3, ks = e >> 12;
    int k = ks * 32 + s * 8 + j;
    float s1 = ibg[c] * rsqrtf(ibv[c] + BNEPS);
    float s2 = pbg[c] * rsqrtf(pbv[c] + BNEPS);
    float w = (k < KIMG) ? img_w[c * KIMG + k] * s1
                         : pts_w[c * PTSC + (k - KIMG)] * s2;
    wg[e] = f2bf(w);
    if (e < OUTC) {
      float t1 = ibg[e] * rsqrtf(ibv[e] + BNEPS);
      float t2 = pbg[e] * rsqrtf(pbv[e] + BNEPS);
      bias[e] = (img_b[e] - ibm[e]) * t1 + ibb[e] +
                (pts_b[e] - pbm[e]) * t2 + pbb[e];
    }
  } else if (e < 57344 + 3 * 294912) {               // conv pack 3*72*4*128*8
    int q = e - 57344;
    int l = q / 294912, r = q % 294912;
    int j = r & 7, c = (r >> 3) & 127, s = (r >> 10) & 3, ks = r >> 12;
    int k = ks * 32 + s * 8 + j;                     // 0..2303
    int tap = k >> 8, ic = k & 255;
    float w = lat_w[(((size_t)l * 128 + c) * 256 + ic) * 9 + tap];
    wc[(size_t)l * 294912 + r] = f2bf(w);
  }
}

// ====== conv implicit-GEMM MFMA, 8 waves (2A+2B+4M each), 3-deep DMA B =====
struct ConvParams {
  int base[4];
  int H[3], W[3], tx[3];
  int poff[3];
  int coff[3];
  int woff[3];
};

__global__ __launch_bounds__(512, 2) void conv_mfma_kernel(
    const u16* __restrict__ pad, const u16* __restrict__ wc,
    const float* __restrict__ lat_b, u16* __restrict__ outbuf, ConvParams P)
{
  __shared__ __attribute__((aligned(16))) u16 sA[6 * 18 * 256];  // 55,296 B
  __shared__ __attribute__((aligned(16))) u16 sB[3 * 4096];      // 24,576 B
  const int bid = blockIdx.x;
  const int lvl = (bid >= P.base[1]) + (bid >= P.base[2]);
  const int local = bid - P.base[lvl];
  const int H = P.H[lvl], W = P.W[lvl], tilesx = P.tx[lvl];
  const int nxy = tilesx * (H >> 2);
  const int b = local / nxy;
  const int r = local % nxy;
  const int ty = r / tilesx, tx = r - ty * tilesx;
  const int y0 = ty * 4, x0 = tx * 16;
  const int Wp = W + 2;
  const u16* __restrict__ pin = pad + P.poff[lvl];
  const u16* __restrict__ wl  = wc + P.woff[lvl];
  u16* __restrict__ outp = outbuf + P.coff[lvl];

  const int t = threadIdx.x, l = t & 63, wv = t >> 6;  // wv 0..7
  const int rp = wv >> 2, ocq = wv & 3;                // row-pair, oc quarter
  const int lr = l & 15, lk = l >> 4;

  auto STAGE = [&](int ks) {
    gload_lds16((const char*)wl + (size_t)ks * 8192 + t * 16,
                (char*)sB + (ks % 3) * 8192 + t * 16);
  };
  STAGE(0); STAGE(1); STAGE(2);

  {
    const int pxi = l >> 5;
    const int bo  = (l & 31) * 16;
    #pragma unroll
    for (int it = 0; it < 7; ++it) {
      const int ch = wv + it * 8;
      if (ch < 54) {
        const int rr2 = ch / 9;
        const int pp  = (ch % 9) * 2;
        const int px  = pp + pxi;
        const u16* src = pin +
            (((size_t)(b * (H + 2) + y0 + rr2) * Wp) + x0 + px) * CIMG + (bo >> 1);
        uint4 v = *(const uint4*)src;
        *(uint4*)((char*)sA + ch * 1024 + pxi * 512 + (bo ^ ((px & 7) << 4))) = v;
      }
    }
  }
  __syncthreads();

  f32x4 acc[2][2] = {};
  bf16x8 Ab[2][2];
  auto loadA = [&](int ks) {
    const int tap = ks >> 3, icc = ks & 7;
    const int ky = tap / 3, kx = tap - ky * 3;
    const int px = lr + kx;
    const int swz = (px & 7) << 4;
    #pragma unroll
    for (int ag = 0; ag < 2; ++ag) {
      const int row = rp * 2 + ag + ky;
      const int ba = (row * 18 + px) * 512 + ((icc * 64 + lk * 16) ^ swz);
      Ab[ks & 1][ag] = *(const bf16x8*)((const char*)sA + ba);
    }
  };
  loadA(0);
  const int bbase = (lk * 128 + ocq * 32 + lr) * 16;

  #pragma unroll
  for (int ks = 0; ks < 72; ++ks) {
    if (ks < 71) loadA(ks + 1);
    const bf16x8 A0 = Ab[ks & 1][0], A1 = Ab[ks & 1][1];
    const char* bb = (const char*)sB + (ks % 3) * 8192 + bbase;
    const bf16x8 B0 = *(const bf16x8*)(bb);
    const bf16x8 B1 = *(const bf16x8*)(bb + 256);
    acc[0][0] = __builtin_amdgcn_mfma_f32_16x16x32_bf16(A0, B0, acc[0][0], 0, 0, 0);
    acc[0][1] = __builtin_amdgcn_mfma_f32_16x16x32_bf16(A0, B1, acc[0][1], 0, 0, 0);
    acc[1][0] = __builtin_amdgcn_mfma_f32_16x16x32_bf16(A1, B0, acc[1][0], 0, 0, 0);
    acc[1][1] = __builtin_amdgcn_mfma_f32_16x16x32_bf16(A1, B1, acc[1][1], 0, 0, 0);
    if (ks < 71) {
      if (ks <= 69) CBAR(1); else CBAR(0);
      if (ks + 3 < 72) STAGE(ks + 3);
    }
  }

  #pragma unroll
  for (int ag = 0; ag < 2; ++ag) {
    const int y = y0 + rp * 2 + ag;
    #pragma unroll
    for (int rr = 0; rr < 4; ++rr) {
      const int x = x0 + lk * 4 + rr;
      if (x < W) {
        const size_t o = ((size_t)(b * H + y) * W + x) * MIDC;
        #pragma unroll
        for (int nf = 0; nf < 2; ++nf) {
          const int oc = ocq * 32 + nf * 16 + lr;
          outp[o + oc] = f2bf(acc[ag][nf][rr] + lat_b[lvl * 128 + oc]);
        }
      }
    }
  }
}

// == FUSED v2 (M=64, 256 thr, 4 waves): direct-to-fragment gather, no sA ====
// Lane (lr,lk) of wave rg gathers its own MFMA A-fragment (8 contiguous
// channels of point row0+rg*16+lr) per K-step; B from 3-deep DMA ring.
__global__ __launch_bounds__(256, 4) void sample_gemm_kernel(
    const float* __restrict__ pts, const float* __restrict__ l2i,
    const float* __restrict__ rot, const float* __restrict__ trans,
    const u16* __restrict__ cbuf,    // conv outs (levels at fixed elem offsets)
    const float* __restrict__ Apts,  // [100000][64] fp32
    const u16*  __restrict__ wg,     // frag-packed [14][4][128][8]
    const float* __restrict__ bias,
    float* __restrict__ outp)        // [100000][128]
{
  __shared__ __attribute__((aligned(16))) u16  sB[3 * 4096];   // 24,576 B
  __shared__ __attribute__((aligned(16))) float sP[192 * 8];   //  6,144 B
  const int t = threadIdx.x;
  const int row0 = blockIdx.x * 64;
  const int l = t & 63, rg = t >> 6;         // wave 0..3 = 16-row group
  const int lr = l & 15, lk = l >> 4;

  // STAGE: DMA one 8KB ks-block of wg into sB[ks%3] (256 thr x 32B = 2 ticks)
  auto STAGE = [&](int ks) {
    const char* src = (const char*)wg + ks * 8192 + t * 16;
    char* dst = (char*)sB + (ks % 3) * 8192 + t * 16;
    gload_lds16(src, dst);
    gload_lds16(src + 4096, dst + 4096);
  };
  STAGE(0); STAGE(1); STAGE(2);      // in flight across phase A

  // ---- phase 0: pts-tail prefetch ----
  const int myrow = min(row0 + rg * 16 + lr, TOTPTS - 1);
  float Pr[2][8];
  #pragma unroll
  for (int s2 = 0; s2 < 2; ++s2) {
    const float* __restrict__ p = Apts + (size_t)myrow * PTSC + s2 * 32 + lk * 8;
    *(float4*)&Pr[s2][0] = *(const float4*)(p);
    *(float4*)&Pr[s2][4] = *(const float4*)(p + 4);
  }

  // ---- phase A: per-(point,level) params (192 tasks) ----
  if (t < 192) {
    const int pt = t & 63, lv = t >> 6;
    const int gpt = min(row0 + pt, TOTPTS - 1);
    const int b = (gpt >= NPTS) ? 1 : 0;
    const float* P = pts + (size_t)gpt * 3;
    const float* T = trans + b * 3;
    const float* R = rot + b * 9;
    const float* L = l2i + b * 16;
    float dx = P[0] - T[0], dy = P[1] - T[1], dz = P[2] - T[2];
    float p0 = dx * R[0] + dy * R[1] + dz * R[2];
    float p1 = dx * R[3] + dy * R[4] + dz * R[5];
    float p2 = dx * R[6] + dy * R[7] + dz * R[8];
    float pc0 = L[0] * p0 + L[1] * p1 + L[2]  * p2 + L[3];
    float pc1 = L[4] * p0 + L[5] * p1 + L[6]  * p2 + L[7];
    float pc2 = L[8] * p0 + L[9] * p1 + L[10] * p2 + L[11];
    float z  = fmaxf(pc2, 1e-5f);
    float gx = pc0 / z / WPADf * 2.f - 1.f;
    float gy = pc1 / z / HPADf * 2.f - 1.f;

    const int Wl = 160 >> lv, Hl = 48 >> lv;
    const float Wm1 = (float)(Wl - 1), Hm1 = (float)(Hl - 1);
    float ix = (gx + 1.f) * 0.5f * Wm1;
    float iy = (gy + 1.f) * 0.5f * Hm1;
    float xf = floorf(ix), yf = floorf(iy);
    float wx1 = ix - xf, wy1 = iy - yf;
    float wx0 = 1.f - wx1, wy0 = 1.f - wy1;
    float ax0 = (xf >= 0.f       && xf <= Wm1)       ? wx0 : 0.f;
    float ax1 = (xf + 1.f >= 0.f && xf + 1.f <= Wm1) ? wx1 : 0.f;
    float ay0 = (yf >= 0.f       && yf <= Hm1)       ? wy0 : 0.f;
    float ay1 = (yf + 1.f >= 0.f && yf + 1.f <= Hm1) ? wy1 : 0.f;
    int xi0 = (int)fminf(fmaxf(xf,       0.f), Wm1);
    int xi1 = (int)fminf(fmaxf(xf + 1.f, 0.f), Wm1);
    int yi0 = (int)fminf(fmaxf(yf,       0.f), Hm1);
    int yi1 = (int)fminf(fmaxf(yf + 1.f, 0.f), Hm1);

    const int foff = (lv == 0) ? 0 : (lv == 1) ? 1966080 : 2457600;  // elems
    const int base = (foff + ((b * Hl + yi0) * Wl + xi0) * MIDC) * 2;
    const int dxB  = (xi1 - xi0) * MIDC * 2;
    const int dyB  = (yi1 - yi0) * Wl * MIDC * 2;

    float* pp = sP + (lv * 64 + pt) * 8;
    pp[0] = ax0 * ay0; pp[1] = ax1 * ay0; pp[2] = ax0 * ay1; pp[3] = ax1 * ay1;
    ((int*)pp)[4] = base; ((int*)pp)[5] = dxB; ((int*)pp)[6] = dyB;
  }
  __syncthreads();   // sP visible; STAGE(0..2) drained (once)

  // ---- main loop: direct-to-fragment gather + MFMA, K = 14 steps ----
  f32x4 acc[8] = {};
  uint4  tq[2][4];                   // tap ring (2-deep, static idx via unroll)
  float4 wts[2];
  const int prow = rg * 16 + lr;     // point within block (= A row)

  auto issueT = [&](int ks) {        // gather 4 taps for img K-step ks
    const int lv = ks >> 2, ksl = ks & 3;
    const float* __restrict__ pp = sP + (lv * 64 + prow) * 8;
    wts[ks & 1] = *(const float4*)pp;
    const int* ip = (const int*)pp;
    const char* __restrict__ src =
        (const char*)cbuf + ip[4] + ksl * 64 + lk * 16;
    const int dxB = ip[5], dyB = ip[6];
    tq[ks & 1][0] = *(const uint4*)(src);
    tq[ks & 1][1] = *(const uint4*)(src + dxB);
    tq[ks & 1][2] = *(const uint4*)(src + dyB);
    tq[ks & 1][3] = *(const uint4*)(src + dxB + dyB);
  };
  issueT(0);

  const int bbase = (lk * 128 + lr) * 16;   // byte off within 8KB sB buf

  #pragma unroll
  for (int ks = 0; ks < 14; ++ks) {
    if (ks + 1 < 12) issueT(ks + 1);
    bf16x8 A0;
    unsigned* au = (unsigned*)&A0;
    if (ks < 12) {
      const float4 w = wts[ks & 1];
      const unsigned* a00 = (const unsigned*)&tq[ks & 1][0];
      const unsigned* a10 = (const unsigned*)&tq[ks & 1][1];
      const unsigned* a01 = (const unsigned*)&tq[ks & 1][2];
      const unsigned* a11 = (const unsigned*)&tq[ks & 1][3];
      #pragma unroll
      for (int jj = 0; jj < 4; ++jj) {
        float rl = blo(a00[jj]) * w.x + blo(a10[jj]) * w.y
                 + blo(a01[jj]) * w.z + blo(a11[jj]) * w.w;
        float rh = bhi(a00[jj]) * w.x + bhi(a10[jj]) * w.y
                 + bhi(a01[jj]) * w.z + bhi(a11[jj]) * w.w;
        au[jj] = cvt_pk_bf16(rl, rh);
      }
    } else {
      #pragma unroll
      for (int jj = 0; jj < 4; ++jj)
        au[jj] = cvt_pk_bf16(Pr[ks - 12][2 * jj], Pr[ks - 12][2 * jj + 1]);
    }
    const char* bb = (const char*)sB + (ks % 3) * 8192 + bbase;
    #pragma unroll
    for (int nf = 0; nf < 8; ++nf) {
      const bf16x8 Bn = *(const bf16x8*)(bb + nf * 256);
      acc[nf] = __builtin_amdgcn_mfma_f32_16x16x32_bf16(A0, Bn, acc[nf], 0, 0, 0);
    }
    if (ks < 13) {
      // outstanding at barrier: STAGE(ks+2)[2 ticks] + taps(ks+1)[4 if ks<=10]
      if (ks <= 10) CBAR(6);
      else if (ks == 11) CBAR(2);
      else CBAR(0);
      if (ks + 3 < 14) STAGE(ks + 3);        // overwrite buf just read (safe)
    }
  }

  #pragma unroll
  for (int rr = 0; rr < 4; ++rr) {
    const int row = row0 + rg * 16 + lk * 4 + rr;
    if (row < TOTPTS) {
      float* __restrict__ po = outp + (size_t)row * OUTC;
      #pragma unroll
      for (int nf = 0; nf < 8; ++nf) {
        const int col = nf * 16 + lr;
        po[col] = fmaxf(acc[nf][rr] + bias[col], 0.f);
      }
    }
  }
}

// ================================= host ====================================
extern "C" void kernel_launch(void* const* d_in, const int* in_sizes, int n_in,
                              void* d_out, int out_size, void* d_ws, size_t ws_size,
                              hipStream_t stream) {
  const float* f0_in  = (const float*)d_in[0];
  const float* f1_in  = (const float*)d_in[1];
  const float* f2_in  = (const float*)d_in[2];
  const float* pts    = (const float*)d_in[3];
  const float* ptsf   = (const float*)d_in[4];
  const float* l2i    = (const float*)d_in[5];
  const float* rot    = (const float*)d_in[6];
  const float* trans  = (const float*)d_in[7];
  const float* lat_w  = (const float*)d_in[8];
  const float* lat_b  = (const float*)d_in[9];
  const float* img_w  = (const float*)d_in[10];
  const float* img_b  = (const float*)d_in[11];
  const float* pts_w  = (const float*)d_in[12];
  const float* pts_b  = (const float*)d_in[13];
  const float* ibg    = (const float*)d_in[14];
  const float* ibbv   = (const float*)d_in[15];
  const float* ibm    = (const float*)d_in[16];
  const float* ibv    = (const float*)d_in[17];
  const float* pbg    = (const float*)d_in[18];
  const float* pbbv   = (const float*)d_in[19];
  const float* pbm    = (const float*)d_in[20];
  const float* pbv    = (const float*)d_in[21];
  float* outp = (float*)d_out;

  uint8_t* ws = (uint8_t*)d_ws;
  const size_t off_wc   = 0;                        // 3*294912 bf16
  const size_t off_wg   = 1769472;                  // 57344 bf16
  const size_t off_bias = 1884160;                  // 128 f32
  const size_t off_c0   = 1884672;
  const size_t off_big  = off_c0 + 3932160 + 983040 + 245760;
  const size_t p0_off = 0;
  const size_t p1_off = 4147200;
  const size_t p2_off = 5238784;

  u16*   wc   = (u16*)(ws + off_wc);
  u16*   wg   = (u16*)(ws + off_wg);
  float* bias = (float*)(ws + off_bias);
  u16*   c0   = (u16*)(ws + off_c0);
  u16*   big  = (u16*)(ws + off_big);

  // 1) zero padded region (+16 KB slack for edge-tile overreads)
  zero_kernel<<<1024, 256, 0, stream>>>((uint4*)big, (5539840 * 2 + 16384) / 16);

  // 2) NCHW f32 -> padded NHWC bf16
  nchw2nhwc_kernel<<<dim3(5, 48, 8), 256, 0, stream>>>(f0_in, big + p0_off, 48, 160);
  nchw2nhwc_kernel<<<dim3(3, 24, 8), 256, 0, stream>>>(f1_in, big + p1_off, 24, 80);
  nchw2nhwc_kernel<<<dim3(2, 12, 8), 256, 0, stream>>>(f2_in, big + p2_off, 12, 40);

  // 3) weight prep
  prep_kernel<<<3680, 256, 0, stream>>>(
      img_w, img_b, pts_w, pts_b, ibg, ibbv, ibm, ibv,
      pbg, pbbv, pbm, pbv, lat_w, wg, wc, bias);

  // 4) conv: 318 blocks x 512 thr (2A+2B wave partition), 3-deep DMA B
  ConvParams P;
  P.base[0] = 0; P.base[1] = 240; P.base[2] = 300; P.base[3] = 318;
  P.H[0] = 48;  P.H[1] = 24; P.H[2] = 12;
  P.W[0] = 160; P.W[1] = 80; P.W[2] = 40;
  P.tx[0] = 10; P.tx[1] = 5;  P.tx[2] = 3;
  P.poff[0] = (int)p0_off; P.poff[1] = (int)p1_off; P.poff[2] = (int)p2_off;
  P.coff[0] = 0; P.coff[1] = 1966080; P.coff[2] = 2457600;
  P.woff[0] = 0; P.woff[1] = 294912;  P.woff[2] = 589824;
  conv_mfma_kernel<<<318, 512, 0, stream>>>(big, wc, lat_b, c0, P);

  // 5) fused sample + GEMM + bias + BN + relu  (M=64 tiles; 1563 blocks)
  sample_gemm_kernel<<<(TOTPTS + 63) / 64, 256, 0, stream>>>(
      pts, l2i, rot, trans, c0, ptsf, wg, bias, outp);

  (void)in_sizes; (void)n_in; (void)out_size; (void)ws_size;
}

// Round 18
// 87.131 us; speedup vs baseline: 1.3048x; 1.3048x over previous
//
#include <hip/hip_runtime.h>
#include <stdint.h>

using u16 = unsigned short;
typedef __attribute__((ext_vector_type(8))) short bf16x8;
typedef __attribute__((ext_vector_type(4))) float f32x4;

#define DEVI static __device__ __forceinline__

constexpr int BATCH  = 2;
constexpr int NPTS   = 50000;
constexpr int TOTPTS = BATCH * NPTS;      // 100000
constexpr int CIMG   = 256;
constexpr int MIDC   = 128;
constexpr int OUTC   = 128;
constexpr int PTSC   = 64;
constexpr int KIMG   = 384;               // 3 * 128
constexpr int KTOT   = 448;
constexpr float WPADf = 1280.f, HPADf = 384.f;
constexpr float BNEPS = 1e-3f;

DEVI u16 f2bf(float f) {                  // RNE float -> bf16 bits (prep paths)
  unsigned x = __float_as_uint(f);
  return (u16)((x + 0x7fffu + ((x >> 16) & 1u)) >> 16);
}
DEVI unsigned cvt_pk_bf16(float lo, float hi) {  // HW packed f32->2xbf16
  unsigned r;
  asm("v_cvt_pk_bf16_f32 %0, %1, %2" : "=v"(r) : "v"(lo), "v"(hi));
  return r;
}
DEVI float blo(unsigned u) { return __uint_as_float(u << 16); }
DEVI float bhi(unsigned u) { return __uint_as_float(u & 0xffff0000u); }

DEVI void gload_lds16(const void* g, void* l) {   // 16B DMA global->LDS
  __builtin_amdgcn_global_load_lds(
      (const __attribute__((address_space(1))) void*)g,
      (__attribute__((address_space(3))) void*)l, 16, 0, 0);
}

// Counted-vmcnt barrier (T4): never drain to 0 in the loop.
#define CBAR(N)                                             \
  do {                                                      \
    asm volatile("s_waitcnt vmcnt(" #N ")" ::: "memory");   \
    __builtin_amdgcn_s_barrier();                           \
    __builtin_amdgcn_sched_barrier(0);                      \
  } while (0)

// ==== NCHW fp32 -> padded NHWC bf16, all levels + borders, ONE dispatch ====
// Writes every element of the padded buffer: interior = transposed input,
// border rows/cols = 0. Replaces zero_kernel + 3 transpose dispatches.
__global__ __launch_bounds__(256) void nhwc_pad_kernel(
    const float* __restrict__ f0, const float* __restrict__ f1,
    const float* __restrict__ f2, u16* __restrict__ big) {
  int y = blockIdx.y;                      // padded row id across levels
  int H, W; const float* in; size_t poff;
  if (y < 50)      { H = 48; W = 160; in = f0; poff = 0; }
  else if (y < 76) { y -= 50; H = 24; W = 80; in = f1; poff = 4147200; }
  else             { y -= 76; H = 12; W = 40; in = f2; poff = 5238784; }
  const int Wp = W + 2;
  const int x0 = blockIdx.x * 32;
  if (x0 >= Wp) return;                    // uniform early-out
  const int t  = threadIdx.x;
  const int b  = blockIdx.z >> 2;
  const int c0 = (blockIdx.z & 3) * 64;
  u16* __restrict__ outp = big + poff;

  __shared__ float s[64][33];
  const bool rowv = (y >= 1) && (y <= H);
  #pragma unroll
  for (int i = 0; i < 8; ++i) {
    int e = t + i * 256, ci = e >> 5, xi = e & 31;
    int xin = x0 + xi - 1;
    float v = 0.f;
    if (rowv && xin >= 0 && xin < W)
      v = in[((size_t)(b * CIMG + c0 + ci) * H + (y - 1)) * W + xin];
    s[ci][xi] = v;
  }
  __syncthreads();
  #pragma unroll
  for (int i = 0; i < 8; ++i) {
    int e = t + i * 256, xi = e >> 6, ci = e & 63;
    if (x0 + xi < Wp)
      outp[((size_t)(b * (H + 2) + y) * Wp + x0 + xi) * CIMG + c0 + ci] =
          f2bf(s[ci][xi]);
  }
}

// ====== prep: BN-fold + bf16 frag-pack of GEMM & conv weights + bias =======
// BOTH packs use layout [ks][s(4)][col(128)][j(8)]  (k = ks*32 + s*8 + j)
__global__ __launch_bounds__(256) void prep_kernel(
    const float* __restrict__ img_w, const float* __restrict__ img_b,
    const float* __restrict__ pts_w, const float* __restrict__ pts_b,
    const float* __restrict__ ibg, const float* __restrict__ ibb,
    const float* __restrict__ ibm, const float* __restrict__ ibv,
    const float* __restrict__ pbg, const float* __restrict__ pbb,
    const float* __restrict__ pbm, const float* __restrict__ pbv,
    const float* __restrict__ lat_w,
    u16* __restrict__ wg, u16* __restrict__ wc, float* __restrict__ bias)
{
  int e = blockIdx.x * 256 + threadIdx.x;
  if (e < 57344) {                                   // GEMM pack 14*4*128*8
    int j = e & 7, c = (e >> 3) & 127, s = (e >> 10) & 3, ks = e >> 12;
    int k = ks * 32 + s * 8 + j;
    float s1 = ibg[c] * rsqrtf(ibv[c] + BNEPS);
    float s2 = pbg[c] * rsqrtf(pbv[c] + BNEPS);
    float w = (k < KIMG) ? img_w[c * KIMG + k] * s1
                         : pts_w[c * PTSC + (k - KIMG)] * s2;
    wg[e] = f2bf(w);
    if (e < OUTC) {
      float t1 = ibg[e] * rsqrtf(ibv[e] + BNEPS);
      float t2 = pbg[e] * rsqrtf(pbv[e] + BNEPS);
      bias[e] = (img_b[e] - ibm[e]) * t1 + ibb[e] +
                (pts_b[e] - pbm[e]) * t2 + pbb[e];
    }
  } else if (e < 57344 + 3 * 294912) {               // conv pack 3*72*4*128*8
    int q = e - 57344;
    int l = q / 294912, r = q % 294912;
    int j = r & 7, c = (r >> 3) & 127, s = (r >> 10) & 3, ks = r >> 12;
    int k = ks * 32 + s * 8 + j;                     // 0..2303
    int tap = k >> 8, ic = k & 255;
    float w = lat_w[(((size_t)l * 128 + c) * 256 + ic) * 9 + tap];
    wc[(size_t)l * 294912 + r] = f2bf(w);
  }
}

// ====== conv implicit-GEMM MFMA, 8 waves (2A+2B+4M each), 3-deep DMA B =====
struct ConvParams {
  int base[4];
  int H[3], W[3], tx[3];
  int poff[3];
  int coff[3];
  int woff[3];
};

__global__ __launch_bounds__(512, 2) void conv_mfma_kernel(
    const u16* __restrict__ pad, const u16* __restrict__ wc,
    const float* __restrict__ lat_b, u16* __restrict__ outbuf, ConvParams P)
{
  __shared__ __attribute__((aligned(16))) u16 sA[6 * 18 * 256];  // 55,296 B
  __shared__ __attribute__((aligned(16))) u16 sB[3 * 4096];      // 24,576 B
  const int bid = blockIdx.x;
  const int lvl = (bid >= P.base[1]) + (bid >= P.base[2]);
  const int local = bid - P.base[lvl];
  const int H = P.H[lvl], W = P.W[lvl], tilesx = P.tx[lvl];
  const int nxy = tilesx * (H >> 2);
  const int b = local / nxy;
  const int r = local % nxy;
  const int ty = r / tilesx, tx = r - ty * tilesx;
  const int y0 = ty * 4, x0 = tx * 16;
  const int Wp = W + 2;
  const u16* __restrict__ pin = pad + P.poff[lvl];
  const u16* __restrict__ wl  = wc + P.woff[lvl];
  u16* __restrict__ outp = outbuf + P.coff[lvl];

  const int t = threadIdx.x, l = t & 63, wv = t >> 6;  // wv 0..7
  const int rp = wv >> 2, ocq = wv & 3;                // row-pair, oc quarter
  const int lr = l & 15, lk = l >> 4;

  auto STAGE = [&](int ks) {
    gload_lds16((const char*)wl + (size_t)ks * 8192 + t * 16,
                (char*)sB + (ks % 3) * 8192 + t * 16);
  };
  STAGE(0); STAGE(1); STAGE(2);

  {
    const int pxi = l >> 5;
    const int bo  = (l & 31) * 16;
    #pragma unroll
    for (int it = 0; it < 7; ++it) {
      const int ch = wv + it * 8;
      if (ch < 54) {
        const int rr2 = ch / 9;
        const int pp  = (ch % 9) * 2;
        const int px  = pp + pxi;
        const u16* src = pin +
            (((size_t)(b * (H + 2) + y0 + rr2) * Wp) + x0 + px) * CIMG + (bo >> 1);
        uint4 v = *(const uint4*)src;
        *(uint4*)((char*)sA + ch * 1024 + pxi * 512 + (bo ^ ((px & 7) << 4))) = v;
      }
    }
  }
  __syncthreads();

  f32x4 acc[2][2] = {};
  bf16x8 Ab[2][2];
  auto loadA = [&](int ks) {
    const int tap = ks >> 3, icc = ks & 7;
    const int ky = tap / 3, kx = tap - ky * 3;
    const int px = lr + kx;
    const int swz = (px & 7) << 4;
    #pragma unroll
    for (int ag = 0; ag < 2; ++ag) {
      const int row = rp * 2 + ag + ky;
      const int ba = (row * 18 + px) * 512 + ((icc * 64 + lk * 16) ^ swz);
      Ab[ks & 1][ag] = *(const bf16x8*)((const char*)sA + ba);
    }
  };
  loadA(0);
  const int bbase = (lk * 128 + ocq * 32 + lr) * 16;

  #pragma unroll
  for (int ks = 0; ks < 72; ++ks) {
    if (ks < 71) loadA(ks + 1);
    const bf16x8 A0 = Ab[ks & 1][0], A1 = Ab[ks & 1][1];
    const char* bb = (const char*)sB + (ks % 3) * 8192 + bbase;
    const bf16x8 B0 = *(const bf16x8*)(bb);
    const bf16x8 B1 = *(const bf16x8*)(bb + 256);
    acc[0][0] = __builtin_amdgcn_mfma_f32_16x16x32_bf16(A0, B0, acc[0][0], 0, 0, 0);
    acc[0][1] = __builtin_amdgcn_mfma_f32_16x16x32_bf16(A0, B1, acc[0][1], 0, 0, 0);
    acc[1][0] = __builtin_amdgcn_mfma_f32_16x16x32_bf16(A1, B0, acc[1][0], 0, 0, 0);
    acc[1][1] = __builtin_amdgcn_mfma_f32_16x16x32_bf16(A1, B1, acc[1][1], 0, 0, 0);
    if (ks < 71) {
      if (ks <= 69) CBAR(1); else CBAR(0);
      if (ks + 3 < 72) STAGE(ks + 3);
    }
  }

  #pragma unroll
  for (int ag = 0; ag < 2; ++ag) {
    const int y = y0 + rp * 2 + ag;
    #pragma unroll
    for (int rr = 0; rr < 4; ++rr) {
      const int x = x0 + lk * 4 + rr;
      if (x < W) {
        const size_t o = ((size_t)(b * H + y) * W + x) * MIDC;
        #pragma unroll
        for (int nf = 0; nf < 2; ++nf) {
          const int oc = ocq * 32 + nf * 16 + lr;
          outp[o + oc] = f2bf(acc[ag][nf][rr] + lat_b[lvl * 128 + oc]);
        }
      }
    }
  }
}

// == FUSED (M=64, 512 thr): params -> gather -> GEMM, 3-deep DMA + vmcnt(1) ==
// (r16 version — known good)
__global__ __launch_bounds__(512, 4) void sample_gemm_kernel(
    const float* __restrict__ pts, const float* __restrict__ l2i,
    const float* __restrict__ rot, const float* __restrict__ trans,
    const u16* __restrict__ cbuf,    // conv outs (levels at fixed elem offsets)
    const float* __restrict__ Apts,  // [100000][64] fp32
    const u16*  __restrict__ wg,     // frag-packed [14][4][128][8]
    const float* __restrict__ bias,
    float* __restrict__ outp)        // [100000][128]
{
  __shared__ __attribute__((aligned(16))) u16  sA[64 * KIMG];  // 49,152 B
  __shared__ __attribute__((aligned(16))) u16  sB[3 * 4096];   // 24,576 B
  __shared__ __attribute__((aligned(16))) float sP[192 * 8];   //  6,144 B
  const int t = threadIdx.x;
  const int row0 = blockIdx.x * 64;
  const int l = t & 63, wv = t >> 6;         // wv 0..7
  const int rg = wv >> 1, wn = wv & 1;       // rg 0..3 (16-row groups)
  const int lr = l & 15, lk = l >> 4;

  auto STAGE = [&](int ks) {
    gload_lds16((const char*)wg + ks * 8192 + t * 16,
                (char*)sB + (ks % 3) * 8192 + t * 16);
  };
  STAGE(0); STAGE(1); STAGE(2);      // in flight across phases A+B

  // ---- phase 0: pts-tail prefetch ----
  const int myrow = min(row0 + rg * 16 + lr, TOTPTS - 1);
  float Pr[2][8];
  #pragma unroll
  for (int s2 = 0; s2 < 2; ++s2) {
    const float* __restrict__ p = Apts + (size_t)myrow * PTSC + s2 * 32 + lk * 8;
    *(float4*)&Pr[s2][0] = *(const float4*)(p);
    *(float4*)&Pr[s2][4] = *(const float4*)(p + 4);
  }

  // ---- phase A: per-(point,level) params (192 tasks) ----
  if (t < 192) {
    const int pt = t & 63, lv = t >> 6;
    const int gpt = min(row0 + pt, TOTPTS - 1);
    const int b = (gpt >= NPTS) ? 1 : 0;
    const float* P = pts + (size_t)gpt * 3;
    const float* T = trans + b * 3;
    const float* R = rot + b * 9;
    const float* L = l2i + b * 16;
    float dx = P[0] - T[0], dy = P[1] - T[1], dz = P[2] - T[2];
    float p0 = dx * R[0] + dy * R[1] + dz * R[2];
    float p1 = dx * R[3] + dy * R[4] + dz * R[5];
    float p2 = dx * R[6] + dy * R[7] + dz * R[8];
    float pc0 = L[0] * p0 + L[1] * p1 + L[2]  * p2 + L[3];
    float pc1 = L[4] * p0 + L[5] * p1 + L[6]  * p2 + L[7];
    float pc2 = L[8] * p0 + L[9] * p1 + L[10] * p2 + L[11];
    float z  = fmaxf(pc2, 1e-5f);
    float gx = pc0 / z / WPADf * 2.f - 1.f;
    float gy = pc1 / z / HPADf * 2.f - 1.f;

    const int Wl = 160 >> lv, Hl = 48 >> lv;
    const float Wm1 = (float)(Wl - 1), Hm1 = (float)(Hl - 1);
    float ix = (gx + 1.f) * 0.5f * Wm1;
    float iy = (gy + 1.f) * 0.5f * Hm1;
    float xf = floorf(ix), yf = floorf(iy);
    float wx1 = ix - xf, wy1 = iy - yf;
    float wx0 = 1.f - wx1, wy0 = 1.f - wy1;
    float ax0 = (xf >= 0.f       && xf <= Wm1)       ? wx0 : 0.f;
    float ax1 = (xf + 1.f >= 0.f && xf + 1.f <= Wm1) ? wx1 : 0.f;
    float ay0 = (yf >= 0.f       && yf <= Hm1)       ? wy0 : 0.f;
    float ay1 = (yf + 1.f >= 0.f && yf + 1.f <= Hm1) ? wy1 : 0.f;
    int xi0 = (int)fminf(fmaxf(xf,       0.f), Wm1);
    int xi1 = (int)fminf(fmaxf(xf + 1.f, 0.f), Wm1);
    int yi0 = (int)fminf(fmaxf(yf,       0.f), Hm1);
    int yi1 = (int)fminf(fmaxf(yf + 1.f, 0.f), Hm1);

    const int foff = (lv == 0) ? 0 : (lv == 1) ? 1966080 : 2457600;  // elems
    const int base = (foff + ((b * Hl + yi0) * Wl + xi0) * MIDC) * 2;
    const int dxB  = (xi1 - xi0) * MIDC * 2;
    const int dyB  = (yi1 - yi0) * Wl * MIDC * 2;

    float* pp = sP + (lv * 64 + pt) * 8;
    pp[0] = ax0 * ay0; pp[1] = ax1 * ay0; pp[2] = ax0 * ay1; pp[3] = ax1 * ay1;
    ((int*)pp)[4] = base; ((int*)pp)[5] = dxB; ((int*)pp)[6] = dyB;
  }
  __syncthreads();

  // ---- phase B: gather, 3-deep ring, cvt_pk pack ----
  {
    const int lane = t & 15, g = t >> 4;     // g 0..31
    uint4 q[3][4];
    float4 wts[3];
    int obyte[3];
    auto issueG = [&](int it) {
      const int s = it % 3;
      const int lv = it >> 1;
      const int pt = (it & 1) * 32 + g;
      const float* __restrict__ pp = sP + (lv * 64 + pt) * 8;
      wts[s] = *(const float4*)pp;
      const int base = ((const int*)pp)[4];
      const int dxB  = ((const int*)pp)[5];
      const int dyB  = ((const int*)pp)[6];
      const char* __restrict__ src = (const char*)cbuf + base + lane * 16;
      q[s][0] = *(const uint4*)(src);
      q[s][1] = *(const uint4*)(src + dxB);
      q[s][2] = *(const uint4*)(src + dyB);
      q[s][3] = *(const uint4*)(src + dxB + dyB);
      const int slot = (lv * 16 + lane) ^ (pt & 7);
      obyte[s] = pt * 768 + slot * 16;
    };
    issueG(0); issueG(1);
    #pragma unroll
    for (int it = 0; it < 6; ++it) {
      if (it + 2 < 6) issueG(it + 2);
      const int s = it % 3;
      const float4 w = wts[s];
      const unsigned* a00 = (const unsigned*)&q[s][0];
      const unsigned* a10 = (const unsigned*)&q[s][1];
      const unsigned* a01 = (const unsigned*)&q[s][2];
      const unsigned* a11 = (const unsigned*)&q[s][3];
      uint4 o;
      unsigned* op = (unsigned*)&o;
      #pragma unroll
      for (int j = 0; j < 4; ++j) {
        float rl = blo(a00[j]) * w.x + blo(a10[j]) * w.y
                 + blo(a01[j]) * w.z + blo(a11[j]) * w.w;
        float rh = bhi(a00[j]) * w.x + bhi(a10[j]) * w.y
                 + bhi(a01[j]) * w.z + bhi(a11[j]) * w.w;
        op[j] = cvt_pk_bf16(rl, rh);
      }
      *(uint4*)((char*)sA + obyte[s]) = o;
    }
  }
  __syncthreads();   // full drain: sB 0..2 ready; sA complete

  // ---- phase 2: GEMM (M=64), A from sA, B from 3-deep DMA sB ----
  f32x4 acc[4] = {};
  bf16x8 Ab[2];
  const int arow = rg * 16 + lr;             // 0..63
  auto loadA = [&](int ks) {
    const int slot = (ks * 4 + lk) ^ (arow & 7);
    Ab[ks & 1] = *(const bf16x8*)((const char*)sA + arow * 768 + slot * 16);
  };
  loadA(0);
  const int bbase = (lk * 128 + wn * 64 + lr) * 16;  // byte off within sB buf

  #pragma unroll
  for (int ks = 0; ks < 14; ++ks) {
    if (ks + 1 < 12) loadA(ks + 1);
    bf16x8 A0;
    if (ks < 12) {
      A0 = Ab[ks & 1];
    } else {
      unsigned* au = (unsigned*)&A0;
      #pragma unroll
      for (int jj = 0; jj < 4; ++jj)
        au[jj] = cvt_pk_bf16(Pr[ks - 12][2 * jj], Pr[ks - 12][2 * jj + 1]);
    }
    const char* bb = (const char*)sB + (ks % 3) * 8192 + bbase;
    const bf16x8 B0 = *(const bf16x8*)(bb);
    const bf16x8 B1 = *(const bf16x8*)(bb + 256);
    const bf16x8 B2 = *(const bf16x8*)(bb + 512);
    const bf16x8 B3 = *(const bf16x8*)(bb + 768);
    acc[0] = __builtin_amdgcn_mfma_f32_16x16x32_bf16(A0, B0, acc[0], 0, 0, 0);
    acc[1] = __builtin_amdgcn_mfma_f32_16x16x32_bf16(A0, B1, acc[1], 0, 0, 0);
    acc[2] = __builtin_amdgcn_mfma_f32_16x16x32_bf16(A0, B2, acc[2], 0, 0, 0);
    acc[3] = __builtin_amdgcn_mfma_f32_16x16x32_bf16(A0, B3, acc[3], 0, 0, 0);
    if (ks < 13) {
      if (ks <= 11) CBAR(1); else CBAR(0);
      if (ks + 3 < 14) STAGE(ks + 3);        // overwrite buf just read (safe)
    }
  }

  #pragma unroll
  for (int rr = 0; rr < 4; ++rr) {
    const int row = row0 + rg * 16 + lk * 4 + rr;
    if (row < TOTPTS) {
      float* __restrict__ po = outp + (size_t)row * OUTC;
      #pragma unroll
      for (int nf = 0; nf < 4; ++nf) {
        const int col = wn * 64 + nf * 16 + lr;
        po[col] = fmaxf(acc[nf][rr] + bias[col], 0.f);
      }
    }
  }
}

// ================================= host ====================================
extern "C" void kernel_launch(void* const* d_in, const int* in_sizes, int n_in,
                              void* d_out, int out_size, void* d_ws, size_t ws_size,
                              hipStream_t stream) {
  const float* f0_in  = (const float*)d_in[0];
  const float* f1_in  = (const float*)d_in[1];
  const float* f2_in  = (const float*)d_in[2];
  const float* pts    = (const float*)d_in[3];
  const float* ptsf   = (const float*)d_in[4];
  const float* l2i    = (const float*)d_in[5];
  const float* rot    = (const float*)d_in[6];
  const float* trans  = (const float*)d_in[7];
  const float* lat_w  = (const float*)d_in[8];
  const float* lat_b  = (const float*)d_in[9];
  const float* img_w  = (const float*)d_in[10];
  const float* img_b  = (const float*)d_in[11];
  const float* pts_w  = (const float*)d_in[12];
  const float* pts_b  = (const float*)d_in[13];
  const float* ibg    = (const float*)d_in[14];
  const float* ibbv   = (const float*)d_in[15];
  const float* ibm    = (const float*)d_in[16];
  const float* ibv    = (const float*)d_in[17];
  const float* pbg    = (const float*)d_in[18];
  const float* pbbv   = (const float*)d_in[19];
  const float* pbm    = (const float*)d_in[20];
  const float* pbv    = (const float*)d_in[21];
  float* outp = (float*)d_out;

  uint8_t* ws = (uint8_t*)d_ws;
  const size_t off_wc   = 0;                        // 3*294912 bf16
  const size_t off_wg   = 1769472;                  // 57344 bf16
  const size_t off_bias = 1884160;                  // 128 f32
  const size_t off_c0   = 1884672;
  const size_t off_big  = off_c0 + 3932160 + 983040 + 245760;
  const size_t p0_off = 0;
  const size_t p1_off = 4147200;
  const size_t p2_off = 5238784;

  u16*   wc   = (u16*)(ws + off_wc);
  u16*   wg   = (u16*)(ws + off_wg);
  float* bias = (float*)(ws + off_bias);
  u16*   c0   = (u16*)(ws + off_c0);
  u16*   big  = (u16*)(ws + off_big);

  // 1) NCHW f32 -> padded NHWC bf16, borders zeroed, ONE dispatch
  nhwc_pad_kernel<<<dim3(6, 90, 8), 256, 0, stream>>>(f0_in, f1_in, f2_in, big);

  // 2) weight prep
  prep_kernel<<<3680, 256, 0, stream>>>(
      img_w, img_b, pts_w, pts_b, ibg, ibbv, ibm, ibv,
      pbg, pbbv, pbm, pbv, lat_w, wg, wc, bias);

  // 3) conv: 318 blocks x 512 thr (2A+2B wave partition), 3-deep DMA B
  ConvParams P;
  P.base[0] = 0; P.base[1] = 240; P.base[2] = 300; P.base[3] = 318;
  P.H[0] = 48;  P.H[1] = 24; P.H[2] = 12;
  P.W[0] = 160; P.W[1] = 80; P.W[2] = 40;
  P.tx[0] = 10; P.tx[1] = 5;  P.tx[2] = 3;
  P.poff[0] = (int)p0_off; P.poff[1] = (int)p1_off; P.poff[2] = (int)p2_off;
  P.coff[0] = 0; P.coff[1] = 1966080; P.coff[2] = 2457600;
  P.woff[0] = 0; P.woff[1] = 294912;  P.woff[2] = 589824;
  conv_mfma_kernel<<<318, 512, 0, stream>>>(big, wc, lat_b, c0, P);

  // 4) fused sample + GEMM + bias + BN + relu  (M=64 tiles; 1563 blocks)
  sample_gemm_kernel<<<(TOTPTS + 63) / 64, 512, 0, stream>>>(
      pts, l2i, rot, trans, c0, ptsf, wg, bias, outp);

  (void)in_sizes; (void)n_in; (void)out_size; (void)ws_size;
}

// Round 19
// 84.351 us; speedup vs baseline: 1.3478x; 1.0330x over previous
//
#include <hip/hip_runtime.h>
#include <stdint.h>

using u16 = unsigned short;
typedef __attribute__((ext_vector_type(8))) short bf16x8;
typedef __attribute__((ext_vector_type(4))) float f32x4;

#define DEVI static __device__ __forceinline__

constexpr int BATCH  = 2;
constexpr int NPTS   = 50000;
constexpr int TOTPTS = BATCH * NPTS;      // 100000
constexpr int CIMG   = 256;
constexpr int MIDC   = 128;
constexpr int OUTC   = 128;
constexpr int PTSC   = 64;
constexpr int KIMG   = 384;               // 3 * 128
constexpr int KTOT   = 448;
constexpr float WPADf = 1280.f, HPADf = 384.f;
constexpr float BNEPS = 1e-3f;

DEVI u16 f2bf(float f) {                  // RNE float -> bf16 bits (prep paths)
  unsigned x = __float_as_uint(f);
  return (u16)((x + 0x7fffu + ((x >> 16) & 1u)) >> 16);
}
DEVI unsigned cvt_pk_bf16(float lo, float hi) {  // HW packed f32->2xbf16
  unsigned r;
  asm("v_cvt_pk_bf16_f32 %0, %1, %2" : "=v"(r) : "v"(lo), "v"(hi));
  return r;
}
DEVI float blo(unsigned u) { return __uint_as_float(u << 16); }
DEVI float bhi(unsigned u) { return __uint_as_float(u & 0xffff0000u); }

DEVI void gload_lds16(const void* g, void* l) {   // 16B DMA global->LDS
  __builtin_amdgcn_global_load_lds(
      (const __attribute__((address_space(1))) void*)g,
      (__attribute__((address_space(3))) void*)l, 16, 0, 0);
}

// Counted-vmcnt barrier (T4): never drain to 0 in the loop.
#define CBAR(N)                                             \
  do {                                                      \
    asm volatile("s_waitcnt vmcnt(" #N ")" ::: "memory");   \
    __builtin_amdgcn_s_barrier();                           \
    __builtin_amdgcn_sched_barrier(0);                      \
  } while (0)

// ==== Combined preamble: padded-NHWC transpose + BN-fold weight prep =======
// Blocks [0, 4320): NCHW fp32 -> padded NHWC bf16 (interior + zero borders).
// Blocks [4320, 8000): GEMM/conv weight frag-pack + fused bias.
// Both packs use layout [ks][s(4)][col(128)][j(8)]  (k = ks*32 + s*8 + j)
__global__ __launch_bounds__(256) void preamble_kernel(
    const float* __restrict__ f0, const float* __restrict__ f1,
    const float* __restrict__ f2, u16* __restrict__ big,
    const float* __restrict__ img_w, const float* __restrict__ img_b,
    const float* __restrict__ pts_w, const float* __restrict__ pts_b,
    const float* __restrict__ ibg, const float* __restrict__ ibb,
    const float* __restrict__ ibm, const float* __restrict__ ibv,
    const float* __restrict__ pbg, const float* __restrict__ pbb,
    const float* __restrict__ pbm, const float* __restrict__ pbv,
    const float* __restrict__ lat_w,
    u16* __restrict__ wg, u16* __restrict__ wc, float* __restrict__ bias)
{
  const int bid = blockIdx.x;
  const int t   = threadIdx.x;
  if (bid < 4320) {
    // ---------------- pad/transpose ----------------
    const int xx = bid % 6;
    int y        = (bid / 6) % 90;
    const int zz = bid / 540;
    int H, W; const float* in; size_t poff;
    if (y < 50)      { H = 48; W = 160; in = f0; poff = 0; }
    else if (y < 76) { y -= 50; H = 24; W = 80; in = f1; poff = 4147200; }
    else             { y -= 76; H = 12; W = 40; in = f2; poff = 5238784; }
    const int Wp = W + 2;
    const int x0 = xx * 32;
    if (x0 >= Wp) return;
    const int b  = zz >> 2;
    const int c0 = (zz & 3) * 64;
    u16* __restrict__ outp = big + poff;

    __shared__ float s[64][33];
    const bool rowv = (y >= 1) && (y <= H);
    #pragma unroll
    for (int i = 0; i < 8; ++i) {
      int e = t + i * 256, ci = e >> 5, xi = e & 31;
      int xin = x0 + xi - 1;
      float v = 0.f;
      if (rowv && xin >= 0 && xin < W)
        v = in[((size_t)(b * CIMG + c0 + ci) * H + (y - 1)) * W + xin];
      s[ci][xi] = v;
    }
    __syncthreads();
    #pragma unroll
    for (int i = 0; i < 8; ++i) {
      int e = t + i * 256, xi = e >> 6, ci = e & 63;
      if (x0 + xi < Wp)
        outp[((size_t)(b * (H + 2) + y) * Wp + x0 + xi) * CIMG + c0 + ci] =
            f2bf(s[ci][xi]);
    }
  } else {
    // ---------------- weight prep ----------------
    int e = (bid - 4320) * 256 + t;
    if (e < 57344) {                                 // GEMM pack 14*4*128*8
      int j = e & 7, c = (e >> 3) & 127, s = (e >> 10) & 3, ks = e >> 12;
      int k = ks * 32 + s * 8 + j;
      float s1 = ibg[c] * rsqrtf(ibv[c] + BNEPS);
      float s2 = pbg[c] * rsqrtf(pbv[c] + BNEPS);
      float w = (k < KIMG) ? img_w[c * KIMG + k] * s1
                           : pts_w[c * PTSC + (k - KIMG)] * s2;
      wg[e] = f2bf(w);
      if (e < OUTC) {
        float t1 = ibg[e] * rsqrtf(ibv[e] + BNEPS);
        float t2 = pbg[e] * rsqrtf(pbv[e] + BNEPS);
        bias[e] = (img_b[e] - ibm[e]) * t1 + ibb[e] +
                  (pts_b[e] - pbm[e]) * t2 + pbb[e];
      }
    } else if (e < 57344 + 3 * 294912) {             // conv pack 3*72*4*128*8
      int q = e - 57344;
      int l = q / 294912, r = q % 294912;
      int j = r & 7, c = (r >> 3) & 127, s = (r >> 10) & 3, ks = r >> 12;
      int k = ks * 32 + s * 8 + j;                   // 0..2303
      int tap = k >> 8, ic = k & 255;
      float w = lat_w[(((size_t)l * 128 + c) * 256 + ic) * 9 + tap];
      wc[(size_t)l * 294912 + r] = f2bf(w);
    }
  }
}

// ====== conv implicit-GEMM MFMA, 8 waves (2A+2B+4M each), 3-deep DMA B =====
struct ConvParams {
  int base[4];
  int H[3], W[3], tx[3];
  int poff[3];
  int coff[3];
  int woff[3];
};

__global__ __launch_bounds__(512, 2) void conv_mfma_kernel(
    const u16* __restrict__ pad, const u16* __restrict__ wc,
    const float* __restrict__ lat_b, u16* __restrict__ outbuf, ConvParams P)
{
  __shared__ __attribute__((aligned(16))) u16 sA[6 * 18 * 256];  // 55,296 B
  __shared__ __attribute__((aligned(16))) u16 sB[3 * 4096];      // 24,576 B
  const int bid = blockIdx.x;
  const int lvl = (bid >= P.base[1]) + (bid >= P.base[2]);
  const int local = bid - P.base[lvl];
  const int H = P.H[lvl], W = P.W[lvl], tilesx = P.tx[lvl];
  const int nxy = tilesx * (H >> 2);
  const int b = local / nxy;
  const int r = local % nxy;
  const int ty = r / tilesx, tx = r - ty * tilesx;
  const int y0 = ty * 4, x0 = tx * 16;
  const int Wp = W + 2;
  const u16* __restrict__ pin = pad + P.poff[lvl];
  const u16* __restrict__ wl  = wc + P.woff[lvl];
  u16* __restrict__ outp = outbuf + P.coff[lvl];

  const int t = threadIdx.x, l = t & 63, wv = t >> 6;  // wv 0..7
  const int rp = wv >> 2, ocq = wv & 3;                // row-pair, oc quarter
  const int lr = l & 15, lk = l >> 4;

  auto STAGE = [&](int ks) {
    gload_lds16((const char*)wl + (size_t)ks * 8192 + t * 16,
                (char*)sB + (ks % 3) * 8192 + t * 16);
  };
  STAGE(0); STAGE(1); STAGE(2);

  {
    const int pxi = l >> 5;
    const int bo  = (l & 31) * 16;
    #pragma unroll
    for (int it = 0; it < 7; ++it) {
      const int ch = wv + it * 8;
      if (ch < 54) {
        const int rr2 = ch / 9;
        const int pp  = (ch % 9) * 2;
        const int px  = pp + pxi;
        const u16* src = pin +
            (((size_t)(b * (H + 2) + y0 + rr2) * Wp) + x0 + px) * CIMG + (bo >> 1);
        uint4 v = *(const uint4*)src;
        *(uint4*)((char*)sA + ch * 1024 + pxi * 512 + (bo ^ ((px & 7) << 4))) = v;
      }
    }
  }
  __syncthreads();

  f32x4 acc[2][2] = {};
  bf16x8 Ab[2][2];
  auto loadA = [&](int ks) {
    const int tap = ks >> 3, icc = ks & 7;
    const int ky = tap / 3, kx = tap - ky * 3;
    const int px = lr + kx;
    const int swz = (px & 7) << 4;
    #pragma unroll
    for (int ag = 0; ag < 2; ++ag) {
      const int row = rp * 2 + ag + ky;
      const int ba = (row * 18 + px) * 512 + ((icc * 64 + lk * 16) ^ swz);
      Ab[ks & 1][ag] = *(const bf16x8*)((const char*)sA + ba);
    }
  };
  loadA(0);
  const int bbase = (lk * 128 + ocq * 32 + lr) * 16;

  #pragma unroll
  for (int ks = 0; ks < 72; ++ks) {
    if (ks < 71) loadA(ks + 1);
    const bf16x8 A0 = Ab[ks & 1][0], A1 = Ab[ks & 1][1];
    const char* bb = (const char*)sB + (ks % 3) * 8192 + bbase;
    const bf16x8 B0 = *(const bf16x8*)(bb);
    const bf16x8 B1 = *(const bf16x8*)(bb + 256);
    acc[0][0] = __builtin_amdgcn_mfma_f32_16x16x32_bf16(A0, B0, acc[0][0], 0, 0, 0);
    acc[0][1] = __builtin_amdgcn_mfma_f32_16x16x32_bf16(A0, B1, acc[0][1], 0, 0, 0);
    acc[1][0] = __builtin_amdgcn_mfma_f32_16x16x32_bf16(A1, B0, acc[1][0], 0, 0, 0);
    acc[1][1] = __builtin_amdgcn_mfma_f32_16x16x32_bf16(A1, B1, acc[1][1], 0, 0, 0);
    if (ks < 71) {
      if (ks <= 69) CBAR(1); else CBAR(0);
      if (ks + 3 < 72) STAGE(ks + 3);
    }
  }

  #pragma unroll
  for (int ag = 0; ag < 2; ++ag) {
    const int y = y0 + rp * 2 + ag;
    #pragma unroll
    for (int rr = 0; rr < 4; ++rr) {
      const int x = x0 + lk * 4 + rr;
      if (x < W) {
        const size_t o = ((size_t)(b * H + y) * W + x) * MIDC;
        #pragma unroll
        for (int nf = 0; nf < 2; ++nf) {
          const int oc = ocq * 32 + nf * 16 + lr;
          outp[o + oc] = f2bf(acc[ag][nf][rr] + lat_b[lvl * 128 + oc]);
        }
      }
    }
  }
}

// == FUSED (M=64, 512 thr): params -> gather -> GEMM, 3-deep DMA + vmcnt(1) ==
__global__ __launch_bounds__(512, 4) void sample_gemm_kernel(
    const float* __restrict__ pts, const float* __restrict__ l2i,
    const float* __restrict__ rot, const float* __restrict__ trans,
    const u16* __restrict__ cbuf,    // conv outs (levels at fixed elem offsets)
    const float* __restrict__ Apts,  // [100000][64] fp32
    const u16*  __restrict__ wg,     // frag-packed [14][4][128][8]
    const float* __restrict__ bias,
    float* __restrict__ outp)        // [100000][128]
{
  __shared__ __attribute__((aligned(16))) u16  sA[64 * KIMG];  // 49,152 B
  __shared__ __attribute__((aligned(16))) u16  sB[3 * 4096];   // 24,576 B
  __shared__ __attribute__((aligned(16))) float sP[192 * 8];   //  6,144 B
  const int t = threadIdx.x;
  const int row0 = blockIdx.x * 64;
  const int l = t & 63, wv = t >> 6;         // wv 0..7
  const int rg = wv >> 1, wn = wv & 1;       // rg 0..3 (16-row groups)
  const int lr = l & 15, lk = l >> 4;

  auto STAGE = [&](int ks) {
    gload_lds16((const char*)wg + ks * 8192 + t * 16,
                (char*)sB + (ks % 3) * 8192 + t * 16);
  };
  STAGE(0); STAGE(1); STAGE(2);      // in flight across phases A+B

  // ---- phase 0: pts-tail prefetch ----
  const int myrow = min(row0 + rg * 16 + lr, TOTPTS - 1);
  float Pr[2][8];
  #pragma unroll
  for (int s2 = 0; s2 < 2; ++s2) {
    const float* __restrict__ p = Apts + (size_t)myrow * PTSC + s2 * 32 + lk * 8;
    *(float4*)&Pr[s2][0] = *(const float4*)(p);
    *(float4*)&Pr[s2][4] = *(const float4*)(p + 4);
  }

  // ---- phase A: per-(point,level) params (192 tasks) ----
  if (t < 192) {
    const int pt = t & 63, lv = t >> 6;
    const int gpt = min(row0 + pt, TOTPTS - 1);
    const int b = (gpt >= NPTS) ? 1 : 0;
    const float* P = pts + (size_t)gpt * 3;
    const float* T = trans + b * 3;
    const float* R = rot + b * 9;
    const float* L = l2i + b * 16;
    float dx = P[0] - T[0], dy = P[1] - T[1], dz = P[2] - T[2];
    float p0 = dx * R[0] + dy * R[1] + dz * R[2];
    float p1 = dx * R[3] + dy * R[4] + dz * R[5];
    float p2 = dx * R[6] + dy * R[7] + dz * R[8];
    float pc0 = L[0] * p0 + L[1] * p1 + L[2]  * p2 + L[3];
    float pc1 = L[4] * p0 + L[5] * p1 + L[6]  * p2 + L[7];
    float pc2 = L[8] * p0 + L[9] * p1 + L[10] * p2 + L[11];
    float z  = fmaxf(pc2, 1e-5f);
    float gx = pc0 / z / WPADf * 2.f - 1.f;
    float gy = pc1 / z / HPADf * 2.f - 1.f;

    const int Wl = 160 >> lv, Hl = 48 >> lv;
    const float Wm1 = (float)(Wl - 1), Hm1 = (float)(Hl - 1);
    float ix = (gx + 1.f) * 0.5f * Wm1;
    float iy = (gy + 1.f) * 0.5f * Hm1;
    float xf = floorf(ix), yf = floorf(iy);
    float wx1 = ix - xf, wy1 = iy - yf;
    float wx0 = 1.f - wx1, wy0 = 1.f - wy1;
    float ax0 = (xf >= 0.f       && xf <= Wm1)       ? wx0 : 0.f;
    float ax1 = (xf + 1.f >= 0.f && xf + 1.f <= Wm1) ? wx1 : 0.f;
    float ay0 = (yf >= 0.f       && yf <= Hm1)       ? wy0 : 0.f;
    float ay1 = (yf + 1.f >= 0.f && yf + 1.f <= Hm1) ? wy1 : 0.f;
    int xi0 = (int)fminf(fmaxf(xf,       0.f), Wm1);
    int xi1 = (int)fminf(fmaxf(xf + 1.f, 0.f), Wm1);
    int yi0 = (int)fminf(fmaxf(yf,       0.f), Hm1);
    int yi1 = (int)fminf(fmaxf(yf + 1.f, 0.f), Hm1);

    const int foff = (lv == 0) ? 0 : (lv == 1) ? 1966080 : 2457600;  // elems
    const int base = (foff + ((b * Hl + yi0) * Wl + xi0) * MIDC) * 2;
    const int dxB  = (xi1 - xi0) * MIDC * 2;
    const int dyB  = (yi1 - yi0) * Wl * MIDC * 2;

    float* pp = sP + (lv * 64 + pt) * 8;
    pp[0] = ax0 * ay0; pp[1] = ax1 * ay0; pp[2] = ax0 * ay1; pp[3] = ax1 * ay1;
    ((int*)pp)[4] = base; ((int*)pp)[5] = dxB; ((int*)pp)[6] = dyB;
  }
  __syncthreads();

  // ---- phase B: gather, 3-deep ring, cvt_pk pack ----
  {
    const int lane = t & 15, g = t >> 4;     // g 0..31
    uint4 q[3][4];
    float4 wts[3];
    int obyte[3];
    auto issueG = [&](int it) {
      const int s = it % 3;
      const int lv = it >> 1;
      const int pt = (it & 1) * 32 + g;
      const float* __restrict__ pp = sP + (lv * 64 + pt) * 8;
      wts[s] = *(const float4*)pp;
      const int base = ((const int*)pp)[4];
      const int dxB  = ((const int*)pp)[5];
      const int dyB  = ((const int*)pp)[6];
      const char* __restrict__ src = (const char*)cbuf + base + lane * 16;
      q[s][0] = *(const uint4*)(src);
      q[s][1] = *(const uint4*)(src + dxB);
      q[s][2] = *(const uint4*)(src + dyB);
      q[s][3] = *(const uint4*)(src + dxB + dyB);
      const int slot = (lv * 16 + lane) ^ (pt & 7);
      obyte[s] = pt * 768 + slot * 16;
    };
    issueG(0); issueG(1);
    #pragma unroll
    for (int it = 0; it < 6; ++it) {
      if (it + 2 < 6) issueG(it + 2);
      const int s = it % 3;
      const float4 w = wts[s];
      const unsigned* a00 = (const unsigned*)&q[s][0];
      const unsigned* a10 = (const unsigned*)&q[s][1];
      const unsigned* a01 = (const unsigned*)&q[s][2];
      const unsigned* a11 = (const unsigned*)&q[s][3];
      uint4 o;
      unsigned* op = (unsigned*)&o;
      #pragma unroll
      for (int j = 0; j < 4; ++j) {
        float rl = blo(a00[j]) * w.x + blo(a10[j]) * w.y
                 + blo(a01[j]) * w.z + blo(a11[j]) * w.w;
        float rh = bhi(a00[j]) * w.x + bhi(a10[j]) * w.y
                 + bhi(a01[j]) * w.z + bhi(a11[j]) * w.w;
        op[j] = cvt_pk_bf16(rl, rh);
      }
      *(uint4*)((char*)sA + obyte[s]) = o;
    }
  }
  __syncthreads();   // full drain: sB 0..2 ready; sA complete

  // ---- phase 2: GEMM (M=64), A from sA, B from 3-deep DMA sB ----
  f32x4 acc[4] = {};
  bf16x8 Ab[2];
  const int arow = rg * 16 + lr;             // 0..63
  auto loadA = [&](int ks) {
    const int slot = (ks * 4 + lk) ^ (arow & 7);
    Ab[ks & 1] = *(const bf16x8*)((const char*)sA + arow * 768 + slot * 16);
  };
  loadA(0);
  const int bbase = (lk * 128 + wn * 64 + lr) * 16;  // byte off within sB buf

  #pragma unroll
  for (int ks = 0; ks < 14; ++ks) {
    if (ks + 1 < 12) loadA(ks + 1);
    bf16x8 A0;
    if (ks < 12) {
      A0 = Ab[ks & 1];
    } else {
      unsigned* au = (unsigned*)&A0;
      #pragma unroll
      for (int jj = 0; jj < 4; ++jj)
        au[jj] = cvt_pk_bf16(Pr[ks - 12][2 * jj], Pr[ks - 12][2 * jj + 1]);
    }
    const char* bb = (const char*)sB + (ks % 3) * 8192 + bbase;
    const bf16x8 B0 = *(const bf16x8*)(bb);
    const bf16x8 B1 = *(const bf16x8*)(bb + 256);
    const bf16x8 B2 = *(const bf16x8*)(bb + 512);
    const bf16x8 B3 = *(const bf16x8*)(bb + 768);
    acc[0] = __builtin_amdgcn_mfma_f32_16x16x32_bf16(A0, B0, acc[0], 0, 0, 0);
    acc[1] = __builtin_amdgcn_mfma_f32_16x16x32_bf16(A0, B1, acc[1], 0, 0, 0);
    acc[2] = __builtin_amdgcn_mfma_f32_16x16x32_bf16(A0, B2, acc[2], 0, 0, 0);
    acc[3] = __builtin_amdgcn_mfma_f32_16x16x32_bf16(A0, B3, acc[3], 0, 0, 0);
    if (ks < 13) {
      if (ks <= 11) CBAR(1); else CBAR(0);
      if (ks + 3 < 14) STAGE(ks + 3);        // overwrite buf just read (safe)
    }
  }

  #pragma unroll
  for (int rr = 0; rr < 4; ++rr) {
    const int row = row0 + rg * 16 + lk * 4 + rr;
    if (row < TOTPTS) {
      float* __restrict__ po = outp + (size_t)row * OUTC;
      #pragma unroll
      for (int nf = 0; nf < 4; ++nf) {
        const int col = wn * 64 + nf * 16 + lr;
        po[col] = fmaxf(acc[nf][rr] + bias[col], 0.f);
      }
    }
  }
}

// ================================= host ====================================
extern "C" void kernel_launch(void* const* d_in, const int* in_sizes, int n_in,
                              void* d_out, int out_size, void* d_ws, size_t ws_size,
                              hipStream_t stream) {
  const float* f0_in  = (const float*)d_in[0];
  const float* f1_in  = (const float*)d_in[1];
  const float* f2_in  = (const float*)d_in[2];
  const float* pts    = (const float*)d_in[3];
  const float* ptsf   = (const float*)d_in[4];
  const float* l2i    = (const float*)d_in[5];
  const float* rot    = (const float*)d_in[6];
  const float* trans  = (const float*)d_in[7];
  const float* lat_w  = (const float*)d_in[8];
  const float* lat_b  = (const float*)d_in[9];
  const float* img_w  = (const float*)d_in[10];
  const float* img_b  = (const float*)d_in[11];
  const float* pts_w  = (const float*)d_in[12];
  const float* pts_b  = (const float*)d_in[13];
  const float* ibg    = (const float*)d_in[14];
  const float* ibbv   = (const float*)d_in[15];
  const float* ibm    = (const float*)d_in[16];
  const float* ibv    = (const float*)d_in[17];
  const float* pbg    = (const float*)d_in[18];
  const float* pbbv   = (const float*)d_in[19];
  const float* pbm    = (const float*)d_in[20];
  const float* pbv    = (const float*)d_in[21];
  float* outp = (float*)d_out;

  uint8_t* ws = (uint8_t*)d_ws;
  const size_t off_wc   = 0;                        // 3*294912 bf16
  const size_t off_wg   = 1769472;                  // 57344 bf16
  const size_t off_bias = 1884160;                  // 128 f32
  const size_t off_c0   = 1884672;
  const size_t off_big  = off_c0 + 3932160 + 983040 + 245760;
  const size_t p0_off = 0;
  const size_t p1_off = 4147200;
  const size_t p2_off = 5238784;

  u16*   wc   = (u16*)(ws + off_wc);
  u16*   wg   = (u16*)(ws + off_wg);
  float* bias = (float*)(ws + off_bias);
  u16*   c0   = (u16*)(ws + off_c0);
  u16*   big  = (u16*)(ws + off_big);

  // 1) preamble: pad/transpose + weight prep, ONE dispatch (8000 blocks)
  preamble_kernel<<<8000, 256, 0, stream>>>(
      f0_in, f1_in, f2_in, big,
      img_w, img_b, pts_w, pts_b, ibg, ibbv, ibm, ibv,
      pbg, pbbv, pbm, pbv, lat_w, wg, wc, bias);

  // 2) conv: 318 blocks x 512 thr (2A+2B wave partition), 3-deep DMA B
  ConvParams P;
  P.base[0] = 0; P.base[1] = 240; P.base[2] = 300; P.base[3] = 318;
  P.H[0] = 48;  P.H[1] = 24; P.H[2] = 12;
  P.W[0] = 160; P.W[1] = 80; P.W[2] = 40;
  P.tx[0] = 10; P.tx[1] = 5;  P.tx[2] = 3;
  P.poff[0] = (int)p0_off; P.poff[1] = (int)p1_off; P.poff[2] = (int)p2_off;
  P.coff[0] = 0; P.coff[1] = 1966080; P.coff[2] = 2457600;
  P.woff[0] = 0; P.woff[1] = 294912;  P.woff[2] = 589824;
  conv_mfma_kernel<<<318, 512, 0, stream>>>(big, wc, lat_b, c0, P);

  // 3) fused sample + GEMM + bias + BN + relu  (M=64 tiles; 1563 blocks)
  sample_gemm_kernel<<<(TOTPTS + 63) / 64, 512, 0, stream>>>(
      pts, l2i, rot, trans, c0, ptsf, wg, bias, outp);

  (void)in_sizes; (void)n_in; (void)out_size; (void)ws_size;
}